// Round 1
// 128.208 us; speedup vs baseline: 1.0030x; 1.0030x over previous
//
#include <hip/hip_runtime.h>
#include <hip/hip_bf16.h>

// TopKPooling, MI355X. Fixed shapes: B=256 graphs x 256 nodes, C=256,
// on_index = even in-graph nodes (128/graph, M=32768), ratio=k=16.
// perm = per-graph top-16 N/O atoms by (score desc, id asc).
// d_out FLOAT32: x_top[1048576] | perm[4096] | score_on[32768] | on_index[32768].
// Uniform per-element threshold -> bf16 MFMA scoring safe (established R1-R6).
// Harness floor: two ~41us poison fills + ~20us d_in restore live in the timed
// window (~103us); our dispatches are the only reducible ~25us.
// R7 change: ONE BLOCK = ONE GRAPH (TM=128, 1024 thr / 16 waves, 128KB LDS,
// 1 block/CU, grid 256 = one CU round) with per-graph top-16 + gather FUSED
// into the same block -> 3rd dispatch eliminated, W L2 re-reads halved
// (106->53 MB), gather rows L2-hot from this block's own staging.

typedef __attribute__((ext_vector_type(8))) short short8v;
typedef __attribute__((ext_vector_type(4))) float float4v;

// ws layout (bytes):
#define W1P_OFF 0         // 16 ntile x 8 kstep x 64 lane x 8 bf16 = 131072 B
#define W2P_OFF 131072    //  8 x 8 x 64 x 8 x 2 = 65536 B
#define W3P_OFF 196608    //  4 x 4 x 64 x 8 x 2 = 16384 B  (total 212992 B)

static __device__ __forceinline__ float lrelu(float z) { return z > 0.0f ? z : 0.1f * z; }

static __device__ __forceinline__ short f2bf(float f) {
    union { float f; unsigned u; } v; v.f = f;
    const unsigned r = v.u + 0x7FFFu + ((v.u >> 16) & 1u);   // round-nearest-even
    return (short)(r >> 16);
}

// Swizzled offset (in shorts) into a [rows][256] bf16 LDS tile.
// 16B chunks XOR'd by row&7 -> b128 A-frag reads hit all 32 banks (2 lanes/bank).
static __device__ __forceinline__ int sw_off(int row, int chunk, int within) {
    return row * 256 + ((chunk ^ (row & 7)) << 3) + within;
}

// Pack W1/W2/W3 into MFMA B-fragment order: unit = (ntile,kstep); within unit,
// lane l holds B[k = (l>>4)*8 + j][n = nt*16 + (l&15)], j=0..7 -> 16B contiguous.
__global__ __launch_bounds__(256) void pack_kernel(
    const float* __restrict__ W1, const float* __restrict__ W2,
    const float* __restrict__ W3, short* __restrict__ ws)
{
    const int u = blockIdx.x * 256 + threadIdx.x;
    if (u >= 13312) return;
    const float* W; int N, unitBase, uu;
    short* dst;
    if (u < 8192)       { W = W1; N = 256; uu = u;         dst = ws + (W1P_OFF/2); unitBase = 8; }
    else if (u < 12288) { W = W2; N = 128; uu = u - 8192;  dst = ws + (W2P_OFF/2); unitBase = 8; }
    else                { W = W3; N = 64;  uu = u - 12288; dst = ws + (W3P_OFF/2); unitBase = 4; }
    const int perNt = unitBase * 64;
    const int nt   = uu / perNt;
    const int rem  = uu % perNt;
    const int ks   = rem / 64;
    const int lane = rem % 64;
    const int q = lane >> 4;
    const int n = nt * 16 + (lane & 15);
    short8v frag;
    #pragma unroll
    for (int j = 0; j < 8; ++j) {
        const int k = ks * 32 + q * 8 + j;
        frag[j] = f2bf(W[(size_t)k * N + n]);
    }
    *(short8v*)(dst + (size_t)uu * 8) = frag;
}

// Fused: 3-layer MLP (bf16 MFMA 16x16x32) + score + per-graph exact stable
// top-16 (rank counting) + x_top gather. One graph (128 on-rows) per block.
// 1024 thr = 16 waves; LDS 128KB+small -> 1 block/CU; grid 256 = one round.
__global__ __launch_bounds__(1024, 4) void fused_mlp_topk_kernel(
    const float* __restrict__ x, const float* __restrict__ pe,
    const float* __restrict__ b1, const float* __restrict__ b2,
    const float* __restrict__ b3, const float* __restrict__ w_atom,
    const int* __restrict__ on_index, const short* __restrict__ ws_pack,
    float* __restrict__ out_perm, float* __restrict__ out_xtop,
    float* __restrict__ out_score, float* __restrict__ out_onidx)
{
    __shared__ __align__(16) short XP[128 * 256];  // xp bf16 -> h2 bf16 -> partials f32
    __shared__ __align__(16) short H1[128 * 256];  // h1 bf16 -> h3 f32
    __shared__ float SC[128];
    __shared__ int   sel_node[16];
    __shared__ float sel_sc[16];

    const int t    = threadIdx.x;
    const int g    = blockIdx.x;      // graph id
    const int m0   = g * 128;         // base into on_index / score arrays
    const int wid  = t >> 6;          // 0..15
    const int lane = t & 63;
    const int q = lane >> 4;          // quad 0..3
    const int c = lane & 15;          // col-in-tile / row-in-tile for A

    const short* W1p = ws_pack + (W1P_OFF / 2);
    const short* W2p = ws_pack + (W2P_OFF / 2);
    const short* W3p = ws_pack + (W3P_OFF / 2);

    // ---- stage xp = bf16(x[node] + pe[node&255]) into XP (swizzled) ----
    #pragma unroll
    for (int i = 0; i < 4; ++i) {
        const int u = t + i * 1024;       // 0..4095
        const int r = u >> 5;             // row 0..127
        const int ck = u & 31;            // 16B chunk 0..31
        const int k = ck << 3;            // col base
        const int node = on_index[m0 + r];
        const float4 xa = *(const float4*)(x + (size_t)node * 256 + k);
        const float4 xb = *(const float4*)(x + (size_t)node * 256 + k + 4);
        const float4 pa = *(const float4*)(pe + (size_t)(node & 255) * 256 + k);
        const float4 pb = *(const float4*)(pe + (size_t)(node & 255) * 256 + k + 4);
        short8v s;
        s[0] = f2bf(xa.x + pa.x); s[1] = f2bf(xa.y + pa.y);
        s[2] = f2bf(xa.z + pa.z); s[3] = f2bf(xa.w + pa.w);
        s[4] = f2bf(xb.x + pb.x); s[5] = f2bf(xb.y + pb.y);
        s[6] = f2bf(xb.z + pb.z); s[7] = f2bf(xb.w + pb.w);
        *(short8v*)(&XP[sw_off(r, ck, 0)]) = s;
    }
    __syncthreads();

    // ---- layer 1: h1 = lrelu(xp @ W1 + b1)  [128 x 256] ----
    // 16 waves -> wave = 1 ntile x 8 mtiles; B-frag loaded once per (nt,ks),
    // reused across 8 mtiles.
    {
        const int nt = wid;   // 0..15
        float4v acc[8];
        const float bb = b1[nt * 16 + c];
        #pragma unroll
        for (int mt = 0; mt < 8; ++mt) acc[mt] = (float4v){bb, bb, bb, bb};
        #pragma unroll
        for (int ks = 0; ks < 8; ++ks) {
            const short8v b = *(const short8v*)(W1p + ((size_t)(nt * 8 + ks) * 64 + lane) * 8);
            #pragma unroll
            for (int mt = 0; mt < 8; ++mt) {
                const short8v a = *(const short8v*)(&XP[sw_off(mt * 16 + c, ks * 4 + q, 0)]);
                acc[mt] = __builtin_amdgcn_mfma_f32_16x16x32_bf16(a, b, acc[mt], 0, 0, 0);
            }
        }
        // epilogue: C/D map col=lane&15, row=q*4+r
        #pragma unroll
        for (int mt = 0; mt < 8; ++mt)
            #pragma unroll
            for (int r = 0; r < 4; ++r) {
                const int row = mt * 16 + q * 4 + r;
                const int col = nt * 16 + c;
                H1[sw_off(row, col >> 3, col & 7)] = f2bf(lrelu(acc[mt][r]));
            }
    }
    __syncthreads();

    // ---- layer 2: h2 = lrelu(h1 @ W2 + b2)  [128 x 128] ----
    // 16 waves -> wave = 1 ntile x 4 mtiles.
    {
        const int nt  = wid & 7;          // 0..7
        const int mt0 = (wid >> 3) * 4;   // 0 or 4
        float4v acc[4];
        const float bb = b2[nt * 16 + c];
        #pragma unroll
        for (int mt = 0; mt < 4; ++mt) acc[mt] = (float4v){bb, bb, bb, bb};
        #pragma unroll
        for (int ks = 0; ks < 8; ++ks) {
            const short8v b = *(const short8v*)(W2p + ((size_t)(nt * 8 + ks) * 64 + lane) * 8);
            #pragma unroll
            for (int mt = 0; mt < 4; ++mt) {
                const short8v a = *(const short8v*)(&H1[sw_off((mt0 + mt) * 16 + c, ks * 4 + q, 0)]);
                acc[mt] = __builtin_amdgcn_mfma_f32_16x16x32_bf16(a, b, acc[mt], 0, 0, 0);
            }
        }
        // XP (xp) dead since barrier-1 -> overwrite with h2 (cols < 128)
        #pragma unroll
        for (int mt = 0; mt < 4; ++mt)
            #pragma unroll
            for (int r = 0; r < 4; ++r) {
                const int row = (mt0 + mt) * 16 + q * 4 + r;
                const int col = nt * 16 + c;
                XP[sw_off(row, col >> 3, col & 7)] = f2bf(lrelu(acc[mt][r]));
            }
    }
    __syncthreads();

    // ---- layer 3: h3 = lrelu(h2 @ W3 + b3)  [128 x 64] ----
    // 16 waves -> nt = wid&3, mtile pair = (wid>>2)*2.
    {
        const int nt  = wid & 3;
        const int mt0 = (wid >> 2) * 2;   // 0,2,4,6
        float4v acc[2];
        const float bb = b3[nt * 16 + c];
        acc[0] = (float4v){bb, bb, bb, bb};
        acc[1] = (float4v){bb, bb, bb, bb};
        #pragma unroll
        for (int ks = 0; ks < 4; ++ks) {
            const short8v b = *(const short8v*)(W3p + ((size_t)(nt * 4 + ks) * 64 + lane) * 8);
            const short8v a0 = *(const short8v*)(&XP[sw_off((mt0 + 0) * 16 + c, ks * 4 + q, 0)]);
            const short8v a1 = *(const short8v*)(&XP[sw_off((mt0 + 1) * 16 + c, ks * 4 + q, 0)]);
            acc[0] = __builtin_amdgcn_mfma_f32_16x16x32_bf16(a0, b, acc[0], 0, 0, 0);
            acc[1] = __builtin_amdgcn_mfma_f32_16x16x32_bf16(a1, b, acc[1], 0, 0, 0);
        }
        // h3 f32 into H1 (H1 last read = layer-2 MFMA, pre-barrier-2 -> safe):
        float* H3F = (float*)H1;   // [128][68] f32 = 34816 B <= 65536
        #pragma unroll
        for (int mt = 0; mt < 2; ++mt)
            #pragma unroll
            for (int r = 0; r < 4; ++r)
                H3F[((mt0 + mt) * 16 + q * 4 + r) * 68 + nt * 16 + c] = lrelu(acc[mt][r]);
    }
    __syncthreads();

    // ---- score = tanh((h3 . w_atom) / ||w_atom||) ----
    {
        const float* H3F = (const float*)H1;
        float* PART = (float*)XP;  // XP last read = layer-3 MFMA, pre-barrier-3 -> safe
        const int r = t >> 3, p = t & 7;   // 128 rows x 8 partial lanes
        float s = 0.0f;
        #pragma unroll
        for (int j = 0; j < 8; ++j) s += H3F[r * 68 + p * 8 + j] * w_atom[p * 8 + j];
        PART[t] = s;
        __syncthreads();
        if (t < 128) {
            float sum = 0.0f;
            #pragma unroll
            for (int pp = 0; pp < 8; ++pp) sum += PART[t * 8 + pp];
            float n2 = 0.0f;
            for (int cc = 0; cc < 64; ++cc) { const float w = w_atom[cc]; n2 += w * w; }
            const float sc = tanhf(sum / sqrtf(n2));
            SC[t] = sc;
            out_score[m0 + t] = sc;
            out_onidx[m0 + t] = (float)on_index[m0 + t];
        }
    }
    __syncthreads();

    // ---- per-graph exact stable top-16 (score desc, id asc) ----
    if (t < 128) {
        const float sj = SC[t];
        int rank = 0;
        for (int i = 0; i < 128; ++i) {
            const float si = SC[i];
            rank += (si > sj) || (si == sj && i < t);
        }
        if (rank < 16) {
            const int node = on_index[m0 + t];
            sel_node[rank] = node;
            sel_sc[rank]   = sj;
            out_perm[g * 16 + rank] = (float)node;
        }
    }
    __syncthreads();

    // ---- gather x_top[g][k][:] = (x[node] + pe[node&255]) * score  (fp32 exact) ----
    // Selected rows were staged by this block moments ago -> L2-hot.
    #pragma unroll
    for (int i = 0; i < 4; ++i) {
        const int idx = t + i * 1024;     // 0..4095 = 16 rows x 256 cols
        const int k   = idx >> 8;
        const int col = idx & 255;
        const int node = sel_node[k];
        const float sc = sel_sc[k];
        const float v = (x[(size_t)node * 256 + col] + pe[(size_t)(node & 255) * 256 + col]) * sc;
        out_xtop[((size_t)(g * 16 + k)) * 256 + col] = v;
    }
}

extern "C" void kernel_launch(void* const* d_in, const int* in_sizes, int n_in,
                              void* d_out, int out_size, void* d_ws, size_t ws_size,
                              hipStream_t stream)
{
    const float* x   = (const float*)d_in[0];
    const float* pe  = (const float*)d_in[1];
    const float* W1  = (const float*)d_in[2];
    const float* b1  = (const float*)d_in[3];
    const float* W2  = (const float*)d_in[4];
    const float* b2  = (const float*)d_in[5];
    const float* W3  = (const float*)d_in[6];
    const float* b3  = (const float*)d_in[7];
    const float* wa  = (const float*)d_in[8];
    const int* on_index = (const int*)d_in[10];

    float* out = (float*)d_out;
    float* out_xtop  = out;
    float* out_perm  = out + 1048576;
    float* out_score = out + 1048576 + 4096;
    float* out_onidx = out + 1048576 + 4096 + 32768;

    short* ws_pack = (short*)d_ws;

    hipLaunchKernelGGL(pack_kernel, dim3(52), dim3(256), 0, stream, W1, W2, W3, ws_pack);
    hipLaunchKernelGGL(fused_mlp_topk_kernel, dim3(256), dim3(1024), 0, stream,
                       x, pe, b1, b2, b3, wa, on_index, (const short*)ws_pack,
                       out_perm, out_xtop, out_score, out_onidx);
}

// Round 3
// 125.548 us; speedup vs baseline: 1.0242x; 1.0212x over previous
//
#include <hip/hip_runtime.h>
#include <hip/hip_bf16.h>

// TopKPooling, MI355X. Fixed shapes: B=256 graphs x 256 nodes, C=256,
// on_index = even in-graph nodes (128/graph, M=32768), ratio=k=16.
// d_out FLOAT32: x_top[1048576] | perm[4096] | score_on[32768] | on_index[32768].
// Harness floor: two ~41us poison fills + d_in restore in the timed window
// (~103us); our dispatches are the only reducible ~25us.
// R8 (resubmitted R9 after infra failure): kernel is LDS-read-bound
// (A-frag traffic 1.66 MB/block ~ 8us/CU).
//  (a) retile: L1 wave=64x32, L2 32x32, L3 32x16 -> A-traffic 896 KB (-46%)
//  (b) swapped-operand MFMA (compute h^T): packed W is bit-identical as the
//      A-operand of W^T, xp A-frag is bit-identical as B-operand of xp^T ->
//      D-frag holds 4 consecutive out-channels of one row -> b64 epilogue
//      stores (4x fewer LDS ops)
//  (c) L3 score partials fused in-register (shfl_xor over q) -> no h3 LDS
//      round-trip; ||w_atom|| precomputed in pack block 52.

typedef __attribute__((ext_vector_type(8))) short short8v;
typedef __attribute__((ext_vector_type(4))) float float4v;

// ws layout (bytes):
#define W1P_OFF 0         // 16 ntile x 8 kstep x 64 lane x 8 bf16 = 131072 B
#define W2P_OFF 131072    //  8 x 8 x 64 x 8 x 2 = 65536 B
#define W3P_OFF 196608    //  4 x 4 x 64 x 8 x 2 = 16384 B
#define NORM_OFF 212992   //  1 f32 = ||w_atom||   (total 212996 B)

static __device__ __forceinline__ float lrelu(float z) { return z > 0.0f ? z : 0.1f * z; }

static __device__ __forceinline__ unsigned f2bfu(float f) {
    union { float f; unsigned u; } v; v.f = f;
    const unsigned r = v.u + 0x7FFFu + ((v.u >> 16) & 1u);   // round-nearest-even
    return r >> 16;
}
static __device__ __forceinline__ short f2bf(float f) { return (short)f2bfu(f); }

// Swizzled offset (in shorts) into a [rows][256] bf16 LDS tile.
// 16B chunks XOR'd by row&7 -> b128 frag reads hit all 32 banks (2 lanes/bank).
static __device__ __forceinline__ int sw_off(int row, int chunk, int within) {
    return row * 256 + ((chunk ^ (row & 7)) << 3) + within;
}

// Pack W1/W2/W3 into MFMA fragment order: unit = (ntile,kstep); within unit,
// lane l holds W[k = (l>>4)*8 + j][n = nt*16 + (l&15)], j=0..7 -> 16B contiguous.
// (Used as the A-operand of W^T in the swapped-operand MFMA: bit-identical.)
// Block 52 additionally computes ||w_atom||.
__global__ __launch_bounds__(256) void pack_kernel(
    const float* __restrict__ W1, const float* __restrict__ W2,
    const float* __restrict__ W3, const float* __restrict__ wa,
    short* __restrict__ ws, float* __restrict__ ws_norm)
{
    const int u = blockIdx.x * 256 + threadIdx.x;
    if (u >= 13312) {
        if (u < 13312 + 64) {
            const int l = u - 13312;
            float w = wa[l];
            float p = w * w;
            #pragma unroll
            for (int s = 1; s < 64; s <<= 1) p += __shfl_xor(p, s);
            if (l == 0) ws_norm[0] = sqrtf(p);
        }
        return;
    }
    const float* W; int N, unitBase, uu;
    short* dst;
    if (u < 8192)       { W = W1; N = 256; uu = u;         dst = ws + (W1P_OFF/2); unitBase = 8; }
    else if (u < 12288) { W = W2; N = 128; uu = u - 8192;  dst = ws + (W2P_OFF/2); unitBase = 8; }
    else                { W = W3; N = 64;  uu = u - 12288; dst = ws + (W3P_OFF/2); unitBase = 4; }
    const int perNt = unitBase * 64;
    const int nt   = uu / perNt;
    const int rem  = uu % perNt;
    const int ks   = rem / 64;
    const int lane = rem % 64;
    const int q = lane >> 4;
    const int n = nt * 16 + (lane & 15);
    short8v frag;
    #pragma unroll
    for (int j = 0; j < 8; ++j) {
        const int k = ks * 32 + q * 8 + j;
        frag[j] = f2bf(W[(size_t)k * N + n]);
    }
    *(short8v*)(dst + (size_t)uu * 8) = frag;
}

// Fused: 3-layer MLP (swapped-operand bf16 MFMA 16x16x32) + score + per-graph
// exact stable top-16 + x_top gather. One graph (128 on-rows) per block.
// 1024 thr = 16 waves; LDS ~131KB -> 1 block/CU; grid 256 = one round.
__global__ __launch_bounds__(1024, 4) void fused_mlp_topk_kernel(
    const float* __restrict__ x, const float* __restrict__ pe,
    const float* __restrict__ b1, const float* __restrict__ b2,
    const float* __restrict__ b3, const float* __restrict__ w_atom,
    const int* __restrict__ on_index, const short* __restrict__ ws_pack,
    const float* __restrict__ ws_norm,
    float* __restrict__ out_perm, float* __restrict__ out_xtop,
    float* __restrict__ out_score, float* __restrict__ out_onidx)
{
    __shared__ __align__(16) short XP[128 * 256];  // xp bf16 -> h2 bf16
    __shared__ __align__(16) short H1[128 * 256];  // h1 bf16
    __shared__ float PART[128][5];                 // per-row q/nt score partials
    __shared__ float SC[128];
    __shared__ int   sel_node[16];
    __shared__ float sel_sc[16];

    const int t    = threadIdx.x;
    const int g    = blockIdx.x;      // graph id
    const int m0   = g * 128;         // base into on_index / score arrays
    const int wid  = t >> 6;          // 0..15
    const int lane = t & 63;
    const int q = lane >> 4;          // quad 0..3
    const int c = lane & 15;          // row-in-tile (D col) / frag row

    const short* W1p = ws_pack + (W1P_OFF / 2);
    const short* W2p = ws_pack + (W2P_OFF / 2);
    const short* W3p = ws_pack + (W3P_OFF / 2);

    // ---- stage xp = bf16(x[node] + pe[node&255]) into XP (swizzled) ----
    #pragma unroll
    for (int i = 0; i < 4; ++i) {
        const int u = t + i * 1024;       // 0..4095
        const int r = u >> 5;             // row 0..127
        const int ck = u & 31;            // 16B chunk 0..31
        const int k = ck << 3;            // col base
        const int node = on_index[m0 + r];
        const float4 xa = *(const float4*)(x + (size_t)node * 256 + k);
        const float4 xb = *(const float4*)(x + (size_t)node * 256 + k + 4);
        const float4 pa = *(const float4*)(pe + (size_t)(node & 255) * 256 + k);
        const float4 pb = *(const float4*)(pe + (size_t)(node & 255) * 256 + k + 4);
        short8v s;
        s[0] = f2bf(xa.x + pa.x); s[1] = f2bf(xa.y + pa.y);
        s[2] = f2bf(xa.z + pa.z); s[3] = f2bf(xa.w + pa.w);
        s[4] = f2bf(xb.x + pb.x); s[5] = f2bf(xb.y + pb.y);
        s[6] = f2bf(xb.z + pb.z); s[7] = f2bf(xb.w + pb.w);
        *(short8v*)(&XP[sw_off(r, ck, 0)]) = s;
    }
    __syncthreads();

    // ---- layer 1: h1 = lrelu(xp @ W1 + b1)  [128 x 256] ----
    // wave = 64 rows x 32 cols (4 mt x 2 nt); xp-frag reused across 2 nt.
    {
        const int mg = wid >> 3;          // 0..1 -> rows mg*64
        const int ng = wid & 7;           // 0..7 -> nt = ng*2+gg
        const int r0 = mg * 64;
        float4v acc[2][4];
        #pragma unroll
        for (int gg = 0; gg < 2; ++gg) {
            const float4 bb = *(const float4*)(b1 + (ng * 2 + gg) * 16 + q * 4);
            #pragma unroll
            for (int mt = 0; mt < 4; ++mt)
                acc[gg][mt] = (float4v){bb.x, bb.y, bb.z, bb.w};
        }
        #pragma unroll
        for (int ks = 0; ks < 8; ++ks) {
            const short8v w0 = *(const short8v*)(W1p + ((size_t)((ng * 2 + 0) * 8 + ks) * 64 + lane) * 8);
            const short8v w1 = *(const short8v*)(W1p + ((size_t)((ng * 2 + 1) * 8 + ks) * 64 + lane) * 8);
            #pragma unroll
            for (int mt = 0; mt < 4; ++mt) {
                const short8v a = *(const short8v*)(&XP[sw_off(r0 + mt * 16 + c, ks * 4 + q, 0)]);
                acc[0][mt] = __builtin_amdgcn_mfma_f32_16x16x32_bf16(w0, a, acc[0][mt], 0, 0, 0);
                acc[1][mt] = __builtin_amdgcn_mfma_f32_16x16x32_bf16(w1, a, acc[1][mt], 0, 0, 0);
            }
        }
        // D-frag (h1^T): lane holds n = nt*16+q*4+r, m = mt*16+c -> b64 store
        #pragma unroll
        for (int gg = 0; gg < 2; ++gg) {
            const int nbase = (ng * 2 + gg) * 16 + q * 4;
            const int chunk = nbase >> 3;
            const int within = nbase & 7;     // 0 or 4 shorts
            #pragma unroll
            for (int mt = 0; mt < 4; ++mt) {
                const int m = r0 + mt * 16 + c;
                uint2 dd;
                dd.x = f2bfu(lrelu(acc[gg][mt][0])) | (f2bfu(lrelu(acc[gg][mt][1])) << 16);
                dd.y = f2bfu(lrelu(acc[gg][mt][2])) | (f2bfu(lrelu(acc[gg][mt][3])) << 16);
                *(uint2*)(&H1[sw_off(m, chunk, within)]) = dd;
            }
        }
    }
    __syncthreads();

    // ---- layer 2: h2 = lrelu(h1 @ W2 + b2)  [128 x 128] ----
    // wave = 32 rows x 32 cols (2 mt x 2 nt).
    {
        const int mg = wid >> 2;          // 0..3 -> rows mg*32
        const int ng = wid & 3;           // 0..3 -> nt = ng*2+gg
        const int r0 = mg * 32;
        float4v acc[2][2];
        #pragma unroll
        for (int gg = 0; gg < 2; ++gg) {
            const float4 bb = *(const float4*)(b2 + (ng * 2 + gg) * 16 + q * 4);
            #pragma unroll
            for (int mt = 0; mt < 2; ++mt)
                acc[gg][mt] = (float4v){bb.x, bb.y, bb.z, bb.w};
        }
        #pragma unroll
        for (int ks = 0; ks < 8; ++ks) {
            const short8v w0 = *(const short8v*)(W2p + ((size_t)((ng * 2 + 0) * 8 + ks) * 64 + lane) * 8);
            const short8v w1 = *(const short8v*)(W2p + ((size_t)((ng * 2 + 1) * 8 + ks) * 64 + lane) * 8);
            #pragma unroll
            for (int mt = 0; mt < 2; ++mt) {
                const short8v a = *(const short8v*)(&H1[sw_off(r0 + mt * 16 + c, ks * 4 + q, 0)]);
                acc[0][mt] = __builtin_amdgcn_mfma_f32_16x16x32_bf16(w0, a, acc[0][mt], 0, 0, 0);
                acc[1][mt] = __builtin_amdgcn_mfma_f32_16x16x32_bf16(w1, a, acc[1][mt], 0, 0, 0);
            }
        }
        // h2 into XP (cols < 128); XP (xp) dead since barrier-1.
        #pragma unroll
        for (int gg = 0; gg < 2; ++gg) {
            const int nbase = (ng * 2 + gg) * 16 + q * 4;
            const int chunk = nbase >> 3;
            const int within = nbase & 7;
            #pragma unroll
            for (int mt = 0; mt < 2; ++mt) {
                const int m = r0 + mt * 16 + c;
                uint2 dd;
                dd.x = f2bfu(lrelu(acc[gg][mt][0])) | (f2bfu(lrelu(acc[gg][mt][1])) << 16);
                dd.y = f2bfu(lrelu(acc[gg][mt][2])) | (f2bfu(lrelu(acc[gg][mt][3])) << 16);
                *(uint2*)(&XP[sw_off(m, chunk, within)]) = dd;
            }
        }
    }
    __syncthreads();

    // ---- layer 3 + score partials: h3 = lrelu(h2 @ W3 + b3) [128 x 64] ----
    // wave = 32 rows x 16 cols; per-lane dot with w_atom[4], shfl-reduce over q.
    {
        const int nt  = wid & 3;
        const int mt0 = (wid >> 2) * 2;   // 0,2,4,6
        float4v acc[2];
        const float4 bb = *(const float4*)(b3 + nt * 16 + q * 4);
        acc[0] = (float4v){bb.x, bb.y, bb.z, bb.w};
        acc[1] = (float4v){bb.x, bb.y, bb.z, bb.w};
        #pragma unroll
        for (int ks = 0; ks < 4; ++ks) {
            const short8v w = *(const short8v*)(W3p + ((size_t)(nt * 4 + ks) * 64 + lane) * 8);
            const short8v a0 = *(const short8v*)(&XP[sw_off((mt0 + 0) * 16 + c, ks * 4 + q, 0)]);
            const short8v a1 = *(const short8v*)(&XP[sw_off((mt0 + 1) * 16 + c, ks * 4 + q, 0)]);
            acc[0] = __builtin_amdgcn_mfma_f32_16x16x32_bf16(w, a0, acc[0], 0, 0, 0);
            acc[1] = __builtin_amdgcn_mfma_f32_16x16x32_bf16(w, a1, acc[1], 0, 0, 0);
        }
        const float4 wv = *(const float4*)(w_atom + nt * 16 + q * 4);
        #pragma unroll
        for (int mt = 0; mt < 2; ++mt) {
            float p = lrelu(acc[mt][0]) * wv.x + lrelu(acc[mt][1]) * wv.y
                    + lrelu(acc[mt][2]) * wv.z + lrelu(acc[mt][3]) * wv.w;
            p += __shfl_xor(p, 16);
            p += __shfl_xor(p, 32);
            if (q == 0) PART[(mt0 + mt) * 16 + c][nt] = p;
        }
    }
    __syncthreads();

    // ---- score = tanh((h3 . w_atom) / ||w_atom||) ----
    if (t < 128) {
        const float sum = PART[t][0] + PART[t][1] + PART[t][2] + PART[t][3];
        const float sc = tanhf(sum / ws_norm[0]);
        SC[t] = sc;
        out_score[m0 + t] = sc;
        out_onidx[m0 + t] = (float)on_index[m0 + t];
    }
    __syncthreads();

    // ---- per-graph exact stable top-16 (score desc, id asc) ----
    if (t < 128) {
        const float sj = SC[t];
        int rank = 0;
        for (int i = 0; i < 128; ++i) {
            const float si = SC[i];
            rank += (si > sj) || (si == sj && i < t);
        }
        if (rank < 16) {
            const int node = on_index[m0 + t];
            sel_node[rank] = node;
            sel_sc[rank]   = sj;
            out_perm[g * 16 + rank] = (float)node;
        }
    }
    __syncthreads();

    // ---- gather x_top[g][k][:] = (x[node] + pe[node&255]) * score  (fp32 exact) ----
    #pragma unroll
    for (int i = 0; i < 4; ++i) {
        const int idx = t + i * 1024;     // 0..4095 = 16 rows x 256 cols
        const int k   = idx >> 8;
        const int col = idx & 255;
        const int node = sel_node[k];
        const float sc = sel_sc[k];
        const float v = (x[(size_t)node * 256 + col] + pe[(size_t)(node & 255) * 256 + col]) * sc;
        out_xtop[((size_t)(g * 16 + k)) * 256 + col] = v;
    }
}

extern "C" void kernel_launch(void* const* d_in, const int* in_sizes, int n_in,
                              void* d_out, int out_size, void* d_ws, size_t ws_size,
                              hipStream_t stream)
{
    const float* x   = (const float*)d_in[0];
    const float* pe  = (const float*)d_in[1];
    const float* W1  = (const float*)d_in[2];
    const float* b1  = (const float*)d_in[3];
    const float* W2  = (const float*)d_in[4];
    const float* b2  = (const float*)d_in[5];
    const float* W3  = (const float*)d_in[6];
    const float* b3  = (const float*)d_in[7];
    const float* wa  = (const float*)d_in[8];
    const int* on_index = (const int*)d_in[10];

    float* out = (float*)d_out;
    float* out_xtop  = out;
    float* out_perm  = out + 1048576;
    float* out_score = out + 1048576 + 4096;
    float* out_onidx = out + 1048576 + 4096 + 32768;

    short* ws_pack = (short*)d_ws;
    float* ws_norm = (float*)((char*)d_ws + NORM_OFF);

    hipLaunchKernelGGL(pack_kernel, dim3(53), dim3(256), 0, stream,
                       W1, W2, W3, wa, ws_pack, ws_norm);
    hipLaunchKernelGGL(fused_mlp_topk_kernel, dim3(256), dim3(1024), 0, stream,
                       x, pe, b1, b2, b3, wa, on_index, (const short*)ws_pack,
                       (const float*)ws_norm,
                       out_perm, out_xtop, out_score, out_onidx);
}

// Round 4
// 125.069 us; speedup vs baseline: 1.0282x; 1.0038x over previous
//
#include <hip/hip_runtime.h>
#include <hip/hip_bf16.h>

// TopKPooling, MI355X. Fixed shapes: B=256 graphs x 256 nodes, C=256,
// on_index = even in-graph nodes (128/graph, M=32768), ratio=k=16.
// d_out FLOAT32: x_top[1048576] | perm[4096] | score_on[32768] | on_index[32768].
// Harness floor: two ~41us poison fills + d_in restore (~103us total).
// R8 (125.5us): LDS-retile + swapped-operand MFMA + in-reg L3 score.
// R10: (a) K-split pipelined staging (T14): stage xp cols 0-127, issue global
//      loads for cols 128-255 into regs, run L1 ks=0-3 (only needs cols 0-127)
//      while prefetch streams, ds_write cols 128-255, barrier, ks=4-7 into the
//      SAME accs. No extra A/W traffic (M-split would double W L2 reads).
//      (b) parallel top-16 rank: 8 threads/score, shfl_xor reduce (was a
//      128-iter serial loop on 2 of 16 waves).

typedef __attribute__((ext_vector_type(8))) short short8v;
typedef __attribute__((ext_vector_type(4))) float float4v;

// ws layout (bytes):
#define W1P_OFF 0         // 16 ntile x 8 kstep x 64 lane x 8 bf16 = 131072 B
#define W2P_OFF 131072    //  8 x 8 x 64 x 8 x 2 = 65536 B
#define W3P_OFF 196608    //  4 x 4 x 64 x 8 x 2 = 16384 B
#define NORM_OFF 212992   //  1 f32 = ||w_atom||   (total 212996 B)

static __device__ __forceinline__ float lrelu(float z) { return z > 0.0f ? z : 0.1f * z; }

static __device__ __forceinline__ unsigned f2bfu(float f) {
    union { float f; unsigned u; } v; v.f = f;
    const unsigned r = v.u + 0x7FFFu + ((v.u >> 16) & 1u);   // round-nearest-even
    return r >> 16;
}
static __device__ __forceinline__ short f2bf(float f) { return (short)f2bfu(f); }

// Swizzled offset (in shorts) into a [rows][256] bf16 LDS tile.
// 16B chunks XOR'd by row&7 -> b128 frag reads hit all 32 banks (2 lanes/bank).
static __device__ __forceinline__ int sw_off(int row, int chunk, int within) {
    return row * 256 + ((chunk ^ (row & 7)) << 3) + within;
}

// Pack W1/W2/W3 into MFMA fragment order: unit = (ntile,kstep); within unit,
// lane l holds W[k = (l>>4)*8 + j][n = nt*16 + (l&15)], j=0..7 -> 16B contiguous.
// (Used as the A-operand of W^T in the swapped-operand MFMA: bit-identical.)
// Tail threads compute ||w_atom||.
__global__ __launch_bounds__(256) void pack_kernel(
    const float* __restrict__ W1, const float* __restrict__ W2,
    const float* __restrict__ W3, const float* __restrict__ wa,
    short* __restrict__ ws, float* __restrict__ ws_norm)
{
    const int u = blockIdx.x * 256 + threadIdx.x;
    if (u >= 13312) {
        if (u < 13312 + 64) {
            const int l = u - 13312;
            float w = wa[l];
            float p = w * w;
            #pragma unroll
            for (int s = 1; s < 64; s <<= 1) p += __shfl_xor(p, s);
            if (l == 0) ws_norm[0] = sqrtf(p);
        }
        return;
    }
    const float* W; int N, unitBase, uu;
    short* dst;
    if (u < 8192)       { W = W1; N = 256; uu = u;         dst = ws + (W1P_OFF/2); unitBase = 8; }
    else if (u < 12288) { W = W2; N = 128; uu = u - 8192;  dst = ws + (W2P_OFF/2); unitBase = 8; }
    else                { W = W3; N = 64;  uu = u - 12288; dst = ws + (W3P_OFF/2); unitBase = 4; }
    const int perNt = unitBase * 64;
    const int nt   = uu / perNt;
    const int rem  = uu % perNt;
    const int ks   = rem / 64;
    const int lane = rem % 64;
    const int q = lane >> 4;
    const int n = nt * 16 + (lane & 15);
    short8v frag;
    #pragma unroll
    for (int j = 0; j < 8; ++j) {
        const int k = ks * 32 + q * 8 + j;
        frag[j] = f2bf(W[(size_t)k * N + n]);
    }
    *(short8v*)(dst + (size_t)uu * 8) = frag;
}

// Fused: 3-layer MLP (swapped-operand bf16 MFMA 16x16x32) + score + per-graph
// exact stable top-16 + x_top gather. One graph (128 on-rows) per block.
// 1024 thr = 16 waves; LDS ~131KB -> 1 block/CU; grid 256 = one round.
__global__ __launch_bounds__(1024, 4) void fused_mlp_topk_kernel(
    const float* __restrict__ x, const float* __restrict__ pe,
    const float* __restrict__ b1, const float* __restrict__ b2,
    const float* __restrict__ b3, const float* __restrict__ w_atom,
    const int* __restrict__ on_index, const short* __restrict__ ws_pack,
    const float* __restrict__ ws_norm,
    float* __restrict__ out_perm, float* __restrict__ out_xtop,
    float* __restrict__ out_score, float* __restrict__ out_onidx)
{
    __shared__ __align__(16) short XP[128 * 256];  // xp bf16 -> h2 bf16
    __shared__ __align__(16) short H1[128 * 256];  // h1 bf16
    __shared__ float PART[128][5];                 // per-row nt score partials
    __shared__ float SC[128];
    __shared__ int   sel_node[16];
    __shared__ float sel_sc[16];

    const int t    = threadIdx.x;
    const int g    = blockIdx.x;      // graph id
    const int m0   = g * 128;         // base into on_index / score arrays
    const int wid  = t >> 6;          // 0..15
    const int lane = t & 63;
    const int q = lane >> 4;          // quad 0..3
    const int c = lane & 15;          // row-in-tile (D col) / frag row

    const short* W1p = ws_pack + (W1P_OFF / 2);
    const short* W2p = ws_pack + (W2P_OFF / 2);
    const short* W3p = ws_pack + (W3P_OFF / 2);

    // ---- stage xp cols 0-127 (chunks 0-15), all 128 rows ----
    // mapping: 16 threads per row -> 512B contiguous per row-group.
    const int rA  = t >> 4;           // 0..63
    const int ckA = t & 15;           // 0..15
    const int kA  = ckA << 3;
    {
        #pragma unroll
        for (int i = 0; i < 2; ++i) {
            const int r = rA + i * 64;
            const int node = on_index[m0 + r];
            const float4 xa = *(const float4*)(x + (size_t)node * 256 + kA);
            const float4 xb = *(const float4*)(x + (size_t)node * 256 + kA + 4);
            const float4 pa = *(const float4*)(pe + (size_t)(node & 255) * 256 + kA);
            const float4 pb = *(const float4*)(pe + (size_t)(node & 255) * 256 + kA + 4);
            short8v s;
            s[0] = f2bf(xa.x + pa.x); s[1] = f2bf(xa.y + pa.y);
            s[2] = f2bf(xa.z + pa.z); s[3] = f2bf(xa.w + pa.w);
            s[4] = f2bf(xb.x + pb.x); s[5] = f2bf(xb.y + pb.y);
            s[6] = f2bf(xb.z + pb.z); s[7] = f2bf(xb.w + pb.w);
            *(short8v*)(&XP[sw_off(r, ckA, 0)]) = s;
        }
    }
    // ---- issue prefetch of cols 128-255 (chunks 16-31) into registers ----
    const int ckB = 16 + (t & 15);
    const int kB  = ckB << 3;
    const int node2 = on_index[m0 + rA];        // rows 0..63
    const int node3 = on_index[m0 + rA + 64];   // rows 64..127
    const float4 xa2 = *(const float4*)(x + (size_t)node2 * 256 + kB);
    const float4 xb2 = *(const float4*)(x + (size_t)node2 * 256 + kB + 4);
    const float4 pa2 = *(const float4*)(pe + (size_t)(node2 & 255) * 256 + kB);
    const float4 pb2 = *(const float4*)(pe + (size_t)(node2 & 255) * 256 + kB + 4);
    const float4 xa3 = *(const float4*)(x + (size_t)node3 * 256 + kB);
    const float4 xb3 = *(const float4*)(x + (size_t)node3 * 256 + kB + 4);
    const float4 pa3 = *(const float4*)(pe + (size_t)(node3 & 255) * 256 + kB);
    const float4 pb3 = *(const float4*)(pe + (size_t)(node3 & 255) * 256 + kB + 4);
    __syncthreads();   // XP cols 0-127 ready

    // ---- layer 1: h1 = lrelu(xp @ W1 + b1)  [128 x 256], K-split ----
    // wave = 64 rows x 32 cols (4 mt x 2 nt); xp-frag reused across 2 nt.
    {
        const int mg = wid >> 3;          // 0..1 -> rows mg*64
        const int ng = wid & 7;           // 0..7 -> nt = ng*2+gg
        const int r0 = mg * 64;
        float4v acc[2][4];
        #pragma unroll
        for (int gg = 0; gg < 2; ++gg) {
            const float4 bb = *(const float4*)(b1 + (ng * 2 + gg) * 16 + q * 4);
            #pragma unroll
            for (int mt = 0; mt < 4; ++mt)
                acc[gg][mt] = (float4v){bb.x, bb.y, bb.z, bb.w};
        }
        // part A: ks 0-3 (reads XP chunks 0-15 only)
        #pragma unroll
        for (int ks = 0; ks < 4; ++ks) {
            const short8v w0 = *(const short8v*)(W1p + ((size_t)((ng * 2 + 0) * 8 + ks) * 64 + lane) * 8);
            const short8v w1 = *(const short8v*)(W1p + ((size_t)((ng * 2 + 1) * 8 + ks) * 64 + lane) * 8);
            #pragma unroll
            for (int mt = 0; mt < 4; ++mt) {
                const short8v a = *(const short8v*)(&XP[sw_off(r0 + mt * 16 + c, ks * 4 + q, 0)]);
                acc[0][mt] = __builtin_amdgcn_mfma_f32_16x16x32_bf16(w0, a, acc[0][mt], 0, 0, 0);
                acc[1][mt] = __builtin_amdgcn_mfma_f32_16x16x32_bf16(w1, a, acc[1][mt], 0, 0, 0);
            }
        }
        // drain prefetch, convert, write XP chunks 16-31 (disjoint from part-A reads)
        {
            short8v s2;
            s2[0] = f2bf(xa2.x + pa2.x); s2[1] = f2bf(xa2.y + pa2.y);
            s2[2] = f2bf(xa2.z + pa2.z); s2[3] = f2bf(xa2.w + pa2.w);
            s2[4] = f2bf(xb2.x + pb2.x); s2[5] = f2bf(xb2.y + pb2.y);
            s2[6] = f2bf(xb2.z + pb2.z); s2[7] = f2bf(xb2.w + pb2.w);
            *(short8v*)(&XP[sw_off(rA, ckB, 0)]) = s2;
            short8v s3;
            s3[0] = f2bf(xa3.x + pa3.x); s3[1] = f2bf(xa3.y + pa3.y);
            s3[2] = f2bf(xa3.z + pa3.z); s3[3] = f2bf(xa3.w + pa3.w);
            s3[4] = f2bf(xb3.x + pb3.x); s3[5] = f2bf(xb3.y + pb3.y);
            s3[6] = f2bf(xb3.z + pb3.z); s3[7] = f2bf(xb3.w + pb3.w);
            *(short8v*)(&XP[sw_off(rA + 64, ckB, 0)]) = s3;
        }
        __syncthreads();   // XP cols 128-255 ready
        // part B: ks 4-7, same accumulators
        #pragma unroll
        for (int ks = 4; ks < 8; ++ks) {
            const short8v w0 = *(const short8v*)(W1p + ((size_t)((ng * 2 + 0) * 8 + ks) * 64 + lane) * 8);
            const short8v w1 = *(const short8v*)(W1p + ((size_t)((ng * 2 + 1) * 8 + ks) * 64 + lane) * 8);
            #pragma unroll
            for (int mt = 0; mt < 4; ++mt) {
                const short8v a = *(const short8v*)(&XP[sw_off(r0 + mt * 16 + c, ks * 4 + q, 0)]);
                acc[0][mt] = __builtin_amdgcn_mfma_f32_16x16x32_bf16(w0, a, acc[0][mt], 0, 0, 0);
                acc[1][mt] = __builtin_amdgcn_mfma_f32_16x16x32_bf16(w1, a, acc[1][mt], 0, 0, 0);
            }
        }
        // D-frag (h1^T): lane holds n = nt*16+q*4+r, m = mt*16+c -> b64 store
        #pragma unroll
        for (int gg = 0; gg < 2; ++gg) {
            const int nbase = (ng * 2 + gg) * 16 + q * 4;
            const int chunk = nbase >> 3;
            const int within = nbase & 7;     // 0 or 4 shorts
            #pragma unroll
            for (int mt = 0; mt < 4; ++mt) {
                const int m = r0 + mt * 16 + c;
                uint2 dd;
                dd.x = f2bfu(lrelu(acc[gg][mt][0])) | (f2bfu(lrelu(acc[gg][mt][1])) << 16);
                dd.y = f2bfu(lrelu(acc[gg][mt][2])) | (f2bfu(lrelu(acc[gg][mt][3])) << 16);
                *(uint2*)(&H1[sw_off(m, chunk, within)]) = dd;
            }
        }
    }
    __syncthreads();

    // ---- layer 2: h2 = lrelu(h1 @ W2 + b2)  [128 x 128] ----
    // wave = 32 rows x 32 cols (2 mt x 2 nt).
    {
        const int mg = wid >> 2;          // 0..3 -> rows mg*32
        const int ng = wid & 3;           // 0..3 -> nt = ng*2+gg
        const int r0 = mg * 32;
        float4v acc[2][2];
        #pragma unroll
        for (int gg = 0; gg < 2; ++gg) {
            const float4 bb = *(const float4*)(b2 + (ng * 2 + gg) * 16 + q * 4);
            #pragma unroll
            for (int mt = 0; mt < 2; ++mt)
                acc[gg][mt] = (float4v){bb.x, bb.y, bb.z, bb.w};
        }
        #pragma unroll
        for (int ks = 0; ks < 8; ++ks) {
            const short8v w0 = *(const short8v*)(W2p + ((size_t)((ng * 2 + 0) * 8 + ks) * 64 + lane) * 8);
            const short8v w1 = *(const short8v*)(W2p + ((size_t)((ng * 2 + 1) * 8 + ks) * 64 + lane) * 8);
            #pragma unroll
            for (int mt = 0; mt < 2; ++mt) {
                const short8v a = *(const short8v*)(&H1[sw_off(r0 + mt * 16 + c, ks * 4 + q, 0)]);
                acc[0][mt] = __builtin_amdgcn_mfma_f32_16x16x32_bf16(w0, a, acc[0][mt], 0, 0, 0);
                acc[1][mt] = __builtin_amdgcn_mfma_f32_16x16x32_bf16(w1, a, acc[1][mt], 0, 0, 0);
            }
        }
        // h2 into XP (cols < 128); XP (xp) dead since L1 done.
        #pragma unroll
        for (int gg = 0; gg < 2; ++gg) {
            const int nbase = (ng * 2 + gg) * 16 + q * 4;
            const int chunk = nbase >> 3;
            const int within = nbase & 7;
            #pragma unroll
            for (int mt = 0; mt < 2; ++mt) {
                const int m = r0 + mt * 16 + c;
                uint2 dd;
                dd.x = f2bfu(lrelu(acc[gg][mt][0])) | (f2bfu(lrelu(acc[gg][mt][1])) << 16);
                dd.y = f2bfu(lrelu(acc[gg][mt][2])) | (f2bfu(lrelu(acc[gg][mt][3])) << 16);
                *(uint2*)(&XP[sw_off(m, chunk, within)]) = dd;
            }
        }
    }
    __syncthreads();

    // ---- layer 3 + score partials: h3 = lrelu(h2 @ W3 + b3) [128 x 64] ----
    // wave = 32 rows x 16 cols; per-lane dot with w_atom[4], shfl-reduce over q.
    {
        const int nt  = wid & 3;
        const int mt0 = (wid >> 2) * 2;   // 0,2,4,6
        float4v acc[2];
        const float4 bb = *(const float4*)(b3 + nt * 16 + q * 4);
        acc[0] = (float4v){bb.x, bb.y, bb.z, bb.w};
        acc[1] = (float4v){bb.x, bb.y, bb.z, bb.w};
        #pragma unroll
        for (int ks = 0; ks < 4; ++ks) {
            const short8v w = *(const short8v*)(W3p + ((size_t)(nt * 4 + ks) * 64 + lane) * 8);
            const short8v a0 = *(const short8v*)(&XP[sw_off((mt0 + 0) * 16 + c, ks * 4 + q, 0)]);
            const short8v a1 = *(const short8v*)(&XP[sw_off((mt0 + 1) * 16 + c, ks * 4 + q, 0)]);
            acc[0] = __builtin_amdgcn_mfma_f32_16x16x32_bf16(w, a0, acc[0], 0, 0, 0);
            acc[1] = __builtin_amdgcn_mfma_f32_16x16x32_bf16(w, a1, acc[1], 0, 0, 0);
        }
        const float4 wv = *(const float4*)(w_atom + nt * 16 + q * 4);
        #pragma unroll
        for (int mt = 0; mt < 2; ++mt) {
            float p = lrelu(acc[mt][0]) * wv.x + lrelu(acc[mt][1]) * wv.y
                    + lrelu(acc[mt][2]) * wv.z + lrelu(acc[mt][3]) * wv.w;
            p += __shfl_xor(p, 16);
            p += __shfl_xor(p, 32);
            if (q == 0) PART[(mt0 + mt) * 16 + c][nt] = p;
        }
    }
    __syncthreads();

    // ---- score = tanh((h3 . w_atom) / ||w_atom||) ----
    if (t < 128) {
        const float sum = PART[t][0] + PART[t][1] + PART[t][2] + PART[t][3];
        const float sc = tanhf(sum / ws_norm[0]);
        SC[t] = sc;
        out_score[m0 + t] = sc;
        out_onidx[m0 + t] = (float)on_index[m0 + t];
    }
    __syncthreads();

    // ---- per-graph exact stable top-16 (score desc, id asc), parallel rank ----
    // 8 threads per score j; each handles 16 comparisons; shfl_xor reduce.
    {
        const int j = t >> 3, p = t & 7;
        const float sj = SC[j];
        int rank = 0;
        #pragma unroll
        for (int ii = 0; ii < 16; ++ii) {
            const int i = p * 16 + ii;
            const float si = SC[i];
            rank += (si > sj) || (si == sj && i < j);
        }
        rank += __shfl_xor(rank, 1);
        rank += __shfl_xor(rank, 2);
        rank += __shfl_xor(rank, 4);
        if (p == 0 && rank < 16) {
            const int node = on_index[m0 + j];
            sel_node[rank] = node;
            sel_sc[rank]   = sj;
            out_perm[g * 16 + rank] = (float)node;
        }
    }
    __syncthreads();

    // ---- gather x_top[g][k][:] = (x[node] + pe[node&255]) * score  (fp32 exact) ----
    #pragma unroll
    for (int i = 0; i < 4; ++i) {
        const int idx = t + i * 1024;     // 0..4095 = 16 rows x 256 cols
        const int k   = idx >> 8;
        const int col = idx & 255;
        const int node = sel_node[k];
        const float sc = sel_sc[k];
        const float v = (x[(size_t)node * 256 + col] + pe[(size_t)(node & 255) * 256 + col]) * sc;
        out_xtop[((size_t)(g * 16 + k)) * 256 + col] = v;
    }
}

extern "C" void kernel_launch(void* const* d_in, const int* in_sizes, int n_in,
                              void* d_out, int out_size, void* d_ws, size_t ws_size,
                              hipStream_t stream)
{
    const float* x   = (const float*)d_in[0];
    const float* pe  = (const float*)d_in[1];
    const float* W1  = (const float*)d_in[2];
    const float* b1  = (const float*)d_in[3];
    const float* W2  = (const float*)d_in[4];
    const float* b2  = (const float*)d_in[5];
    const float* W3  = (const float*)d_in[6];
    const float* b3  = (const float*)d_in[7];
    const float* wa  = (const float*)d_in[8];
    const int* on_index = (const int*)d_in[10];

    float* out = (float*)d_out;
    float* out_xtop  = out;
    float* out_perm  = out + 1048576;
    float* out_score = out + 1048576 + 4096;
    float* out_onidx = out + 1048576 + 4096 + 32768;

    short* ws_pack = (short*)d_ws;
    float* ws_norm = (float*)((char*)d_ws + NORM_OFF);

    hipLaunchKernelGGL(pack_kernel, dim3(53), dim3(256), 0, stream,
                       W1, W2, W3, wa, ws_pack, ws_norm);
    hipLaunchKernelGGL(fused_mlp_topk_kernel, dim3(256), dim3(1024), 0, stream,
                       x, pe, b1, b2, b3, wa, on_index, (const short*)ws_pack,
                       (const float*)ws_norm,
                       out_perm, out_xtop, out_score, out_onidx);
}